// Round 1
// baseline (127.545 us; speedup 1.0000x reference)
//
#include <hip/hip_runtime.h>

__device__ __forceinline__ float clip01(float x) {
    return fminf(fmaxf(x, 0.0f), 1.0f);
}

__device__ __forceinline__ void fma4(float4& a, const float4 v, const float s) {
    a.x = fmaf(v.x, s, a.x);
    a.y = fmaf(v.y, s, a.y);
    a.z = fmaf(v.z, s, a.z);
    a.w = fmaf(v.w, s, a.w);
}

__device__ __forceinline__ float4 add4(const float4 a, const float4 b) {
    return make_float4(a.x + b.x, a.y + b.y, a.z + b.z, a.w + b.w);
}

// Dims: L1=3072, FT_OUT=3080 (L1 + 8 psqt), L2=15, L3=32, NUM_LS=8, MAX_ACTIVE=32
__global__ __launch_bounds__(256) void nnue_fwd(
    const float* __restrict__ us_p,
    const float* __restrict__ them_p,
    const int*   __restrict__ wIdx,
    const float* __restrict__ wVal,
    const int*   __restrict__ bIdx,
    const float* __restrict__ bVal,
    const int*   __restrict__ psqtIdx,
    const int*   __restrict__ lsIdx,
    const float* __restrict__ ftw,   // (22528, 3080)
    const float* __restrict__ ftb,   // (3080,)
    const float* __restrict__ W1,    // (8, 16, 3072)
    const float* __restrict__ b1,    // (8, 16)
    const float* __restrict__ W2,    // (8, 32, 30)
    const float* __restrict__ b2,    // (8, 32)
    const float* __restrict__ W3,    // (8, 1, 32)
    const float* __restrict__ b3,    // (8, 1)
    float* __restrict__ out)         // (B, 1)
{
    __shared__ __align__(16) float sw[3080];   // white accumulator (+bias)
    __shared__ __align__(16) float sb[3080];   // black accumulator (+bias)
    __shared__ __align__(16) float sl0[3072];  // activation output
    __shared__ float sl1[16];                  // W1 output

    const int b   = blockIdx.x;
    const int tid = threadIdx.x;

    // ---------------- Phase 1: feature-transform gather-accumulate ----------------
    // float4 lanes: d = tid*4 + i*1024 ; i=0..2 covers 0..3071 ; tail (tid<2) covers 3072..3079
    float4 aw0 = {0,0,0,0}, aw1 = {0,0,0,0}, aw2 = {0,0,0,0}, awt = {0,0,0,0};
    float4 ab0 = {0,0,0,0}, ab1 = {0,0,0,0}, ab2 = {0,0,0,0}, abt = {0,0,0,0};

    const int*   wIp = wIdx + b * 32;
    const float* wVp = wVal + b * 32;
    const int*   bIp = bIdx + b * 32;
    const float* bVp = bVal + b * 32;

    for (int f = 0; f < 32; ++f) {
        const int   iw = wIp[f];
        const float vw = wVp[f];
        const int   ib = bIp[f];
        const float vb = bVp[f];
        const float4* rw = reinterpret_cast<const float4*>(ftw + (size_t)iw * 3080);
        const float4* rb = reinterpret_cast<const float4*>(ftw + (size_t)ib * 3080);

        float4 x0 = rw[tid];
        float4 x1 = rw[tid + 256];
        float4 x2 = rw[tid + 512];
        float4 y0 = rb[tid];
        float4 y1 = rb[tid + 256];
        float4 y2 = rb[tid + 512];
        fma4(aw0, x0, vw); fma4(aw1, x1, vw); fma4(aw2, x2, vw);
        fma4(ab0, y0, vb); fma4(ab1, y1, vb); fma4(ab2, y2, vb);
        if (tid < 2) {
            float4 xt = rw[768 + tid];
            float4 yt = rb[768 + tid];
            fma4(awt, xt, vw);
            fma4(abt, yt, vb);
        }
    }

    {
        const float4* bv  = reinterpret_cast<const float4*>(ftb);
        float4* swv = reinterpret_cast<float4*>(sw);
        float4* sbv = reinterpret_cast<float4*>(sb);
        float4 bb;
        bb = bv[tid];       swv[tid]       = add4(aw0, bb); sbv[tid]       = add4(ab0, bb);
        bb = bv[tid + 256]; swv[tid + 256] = add4(aw1, bb); sbv[tid + 256] = add4(ab1, bb);
        bb = bv[tid + 512]; swv[tid + 512] = add4(aw2, bb); sbv[tid + 512] = add4(ab2, bb);
        if (tid < 2) {
            bb = bv[768 + tid];
            swv[768 + tid] = add4(awt, bb);
            sbv[768 + tid] = add4(abt, bb);
        }
    }
    __syncthreads();

    // ---------------- Phase 2: l0 = clip(us*[w,b]+them*[b,w]); pairwise products ----------------
    const float u  = us_p[b];
    const float th = them_p[b];
    const float cmul = 127.0f / 128.0f;
    #pragma unroll
    for (int s = 0; s < 6; ++s) {
        const int j = tid + s * 256;           // 0..1535
        const float w0 = sw[j],        w1 = sw[j + 1536];
        const float v0 = sb[j],        v1 = sb[j + 1536];
        const float a0 = clip01(u * w0 + th * v0);
        const float a1 = clip01(u * w1 + th * v1);
        const float c0 = clip01(u * v0 + th * w0);
        const float c1 = clip01(u * v1 + th * w1);
        sl0[j]        = a0 * a1 * cmul;
        sl0[1536 + j] = c0 * c1 * cmul;
    }
    __syncthreads();

    // ---------------- Phase 3: l1 = W1[li] @ l0 + b1[li]  (16 x 3072 matvec) ----------------
    const int li = lsIdx[b];
    const float* W1b = W1 + (size_t)li * 16 * 3072;
    const int wave = tid >> 6;
    const int lane = tid & 63;
    const float4* l0v = reinterpret_cast<const float4*>(sl0);
    #pragma unroll
    for (int r0 = 0; r0 < 4; ++r0) {
        const int row = wave * 4 + r0;
        const float4* wr = reinterpret_cast<const float4*>(W1b + row * 3072);
        float acc = 0.0f;
        #pragma unroll
        for (int it = 0; it < 12; ++it) {
            const float4 a = wr[lane + it * 64];
            const float4 x = l0v[lane + it * 64];
            acc = fmaf(a.x, x.x, acc);
            acc = fmaf(a.y, x.y, acc);
            acc = fmaf(a.z, x.z, acc);
            acc = fmaf(a.w, x.w, acc);
        }
        #pragma unroll
        for (int off = 32; off > 0; off >>= 1) acc += __shfl_down(acc, off);
        if (lane == 0) sl1[row] = acc + b1[li * 16 + row];
    }
    __syncthreads();

    // ---------------- Phase 4: tail MLP on wave 0 ----------------
    if (wave == 0) {
        float p = 0.0f;
        if (lane < 32) {
            const float* W2r = W2 + ((size_t)li * 32 + lane) * 30;
            float acc = b2[li * 32 + lane];
            #pragma unroll
            for (int i = 0; i < 30; ++i) {
                float v = (i < 15) ? sl1[i] * sl1[i] : sl1[i - 15];
                v = clip01(v);
                acc = fmaf(W2r[i], v, acc);
            }
            const float l2x = clip01(acc);
            p = l2x * W3[li * 32 + lane];
        }
        #pragma unroll
        for (int off = 32; off > 0; off >>= 1) p += __shfl_down(p, off);
        if (lane == 0) {
            const float l1y = sl1[15];
            const int   pi  = psqtIdx[b];
            const float wps = sw[3072 + pi];
            const float bps = sb[3072 + pi];
            out[b] = p + b3[li] + l1y + (wps - bps) * (u - 0.5f);
        }
    }
}

extern "C" void kernel_launch(void* const* d_in, const int* in_sizes, int n_in,
                              void* d_out, int out_size, void* d_ws, size_t ws_size,
                              hipStream_t stream) {
    const float* us_p   = (const float*)d_in[0];
    const float* them_p = (const float*)d_in[1];
    const int*   wIdx   = (const int*)d_in[2];
    const float* wVal   = (const float*)d_in[3];
    const int*   bIdx   = (const int*)d_in[4];
    const float* bVal   = (const float*)d_in[5];
    const int*   psqtI  = (const int*)d_in[6];
    const int*   lsI    = (const int*)d_in[7];
    const float* ftw    = (const float*)d_in[8];
    const float* ftb    = (const float*)d_in[9];
    const float* W1     = (const float*)d_in[10];
    const float* b1     = (const float*)d_in[11];
    const float* W2     = (const float*)d_in[12];
    const float* b2     = (const float*)d_in[13];
    const float* W3     = (const float*)d_in[14];
    const float* b3     = (const float*)d_in[15];
    float* out = (float*)d_out;

    const int B = in_sizes[0];   // us is (B,1)
    nnue_fwd<<<B, 256, 0, stream>>>(us_p, them_p, wIdx, wVal, bIdx, bVal,
                                    psqtI, lsI, ftw, ftb, W1, b1, W2, b2, W3, b3, out);
}